// Round 1
// baseline (2066.972 us; speedup 1.0000x reference)
//
#include <hip/hip_runtime.h>

// Problem dims (fixed by setup_inputs)
#define Bb 8
#define Tt 2048
#define Hh 1024
#define Kk 256
#define Vv 256
#define Oo 1024

typedef __attribute__((ext_vector_type(8))) __bf16 bf16x8;
typedef __attribute__((ext_vector_type(4))) float f32x4;

__device__ __forceinline__ unsigned short f2b(float f) {
  unsigned u = __float_as_uint(f);
  u = (u + 0x7FFFu + ((u >> 16) & 1u)) >> 16;
  return (unsigned short)u;
}
__device__ __forceinline__ float b2f(unsigned short u) {
  return __uint_as_float(((unsigned)u) << 16);
}

// ---------------- cast f32 -> bf16 (vectorized) ----------------
__global__ __launch_bounds__(256) void cast_bf16_kernel(const float* __restrict__ in,
                                                        unsigned short* __restrict__ out,
                                                        int n4) {
  int i = blockIdx.x * 256 + threadIdx.x;
  if (i >= n4) return;
  float4 v = ((const float4*)in)[i];
  ushort4 o;
  o.x = f2b(v.x); o.y = f2b(v.y); o.z = f2b(v.z); o.w = f2b(v.w);
  ((ushort4*)out)[i] = o;
}

// ---------------- transpose + cast: W (H x N) f32 -> WT (N x H) bf16 ----------------
__global__ __launch_bounds__(256) void transpose_cast_kernel(const float* __restrict__ W,
                                                             unsigned short* __restrict__ WT,
                                                             int H, int N) {
  __shared__ float tile[32][33];
  int h0 = blockIdx.x * 32, n0 = blockIdx.y * 32;
  int tx = threadIdx.x & 31, ty = threadIdx.x >> 5;  // 32 x 8
  for (int r = ty; r < 32; r += 8)
    tile[r][tx] = W[(size_t)(h0 + r) * N + n0 + tx];
  __syncthreads();
  for (int r = ty; r < 32; r += 8)
    WT[(size_t)(n0 + r) * H + h0 + tx] = f2b(tile[tx][r]);
}

// ---------------- bf16 MFMA GEMM: C = A (MxK) * Bt^T (Bt is NxK) + bias ----------------
// mode 0: f32 out, 1: bf16 out, 2: bf16 out + sigmoid
#define BM 128
#define BN 128
#define BKK 32
#define LDK 40  // padded K leading dim (breaks 64B-stride bank conflicts)

__global__ __launch_bounds__(256) void gemm_bt_kernel(
    const unsigned short* __restrict__ A,
    const unsigned short* __restrict__ Bt,
    const float* __restrict__ bias,
    float* __restrict__ Cf,
    unsigned short* __restrict__ Cb,
    int M, int N, int K, int mode) {
  __shared__ __align__(16) unsigned short As[BM][LDK];
  __shared__ __align__(16) unsigned short Bs[BN][LDK];
  const int tid = threadIdx.x;
  const int lane = tid & 63, wid = tid >> 6;
  const int wm = wid >> 1, wn = wid & 1;  // 2x2 wave grid, each wave 64x64
  const int m0 = blockIdx.y * BM, n0 = blockIdx.x * BN;
  const int sr = tid >> 1, sc = (tid & 1) * 16;
  const int fr = lane & 15, fk = (lane >> 4) * 8;
  f32x4 acc[4][4] = {};
  for (int k0 = 0; k0 < K; k0 += BKK) {
    const unsigned short* ap = A + (size_t)(m0 + sr) * K + k0 + sc;
    const unsigned short* bp = Bt + (size_t)(n0 + sr) * K + k0 + sc;
    uint4 a0 = *(const uint4*)ap;
    uint4 a1 = *(const uint4*)(ap + 8);
    uint4 b0 = *(const uint4*)bp;
    uint4 b1 = *(const uint4*)(bp + 8);
    __syncthreads();  // previous iter's frag reads done
    *(uint4*)&As[sr][sc] = a0;
    *(uint4*)&As[sr][sc + 8] = a1;
    *(uint4*)&Bs[sr][sc] = b0;
    *(uint4*)&Bs[sr][sc + 8] = b1;
    __syncthreads();
    bf16x8 af[4], bfv[4];
#pragma unroll
    for (int i = 0; i < 4; ++i)
      af[i] = *(const bf16x8*)&As[wm * 64 + i * 16 + fr][fk];
#pragma unroll
    for (int i = 0; i < 4; ++i)
      bfv[i] = *(const bf16x8*)&Bs[wn * 64 + i * 16 + fr][fk];
#pragma unroll
    for (int i = 0; i < 4; ++i)
#pragma unroll
      for (int j = 0; j < 4; ++j)
        acc[i][j] = __builtin_amdgcn_mfma_f32_16x16x32_bf16(af[i], bfv[j], acc[i][j], 0, 0, 0);
  }
  const int fq = lane >> 4;
#pragma unroll
  for (int j = 0; j < 4; ++j) {
    int n = n0 + wn * 64 + j * 16 + fr;
    float bv = bias[n];
#pragma unroll
    for (int i = 0; i < 4; ++i) {
      int mb = m0 + wm * 64 + i * 16 + fq * 4;
#pragma unroll
      for (int r = 0; r < 4; ++r) {
        float x = acc[i][j][r] + bv;
        if (mode == 2) x = 1.f / (1.f + expf(-x));
        if (mode == 0) Cf[(size_t)(mb + r) * N + n] = x;
        else Cb[(size_t)(mb + r) * N + n] = f2b(x);
      }
    }
  }
}

// ---------------- sequential gated scan over T ----------------
// grid: (Vv/VT, Bb), 256 threads; thread owns k=tid, VT v-columns of state.
#define VT 8
__global__ __launch_bounds__(256) void scan_kernel(
    const unsigned short* __restrict__ q, const unsigned short* __restrict__ kf,
    const unsigned short* __restrict__ g, const unsigned short* __restrict__ v,
    unsigned short* __restrict__ att, float* __restrict__ state_out) {
  const int b = blockIdx.y;
  const int v0 = blockIdx.x * VT;
  const int kt = threadIdx.x;  // k index 0..255
  const int lane = kt & 63, wv = kt >> 6;
  float st[VT];
#pragma unroll
  for (int j = 0; j < VT; ++j) st[j] = 0.f;
  __shared__ float red[2][4][VT];
  for (int t = 0; t < Tt; ++t) {
    size_t base = (size_t)b * Tt + t;
    float qv = b2f(q[base * Kk + kt]);
    float kv = b2f(kf[base * Kk + kt]);
    float gv = b2f(g[base * Kk + kt]);
    // v broadcast: 8 bf16 = 16B
    uint4 vl = *(const uint4*)(v + base * Vv + v0);
    unsigned w0 = vl.x, w1 = vl.y, w2 = vl.z, w3 = vl.w;
    float vv[8];
    vv[0] = __uint_as_float(w0 << 16); vv[1] = __uint_as_float(w0 & 0xFFFF0000u);
    vv[2] = __uint_as_float(w1 << 16); vv[3] = __uint_as_float(w1 & 0xFFFF0000u);
    vv[4] = __uint_as_float(w2 << 16); vv[5] = __uint_as_float(w2 & 0xFFFF0000u);
    vv[6] = __uint_as_float(w3 << 16); vv[7] = __uint_as_float(w3 & 0xFFFF0000u);
    float po[VT];
#pragma unroll
    for (int j = 0; j < VT; ++j) {
      st[j] = st[j] * gv + kv * vv[j];
      po[j] = qv * st[j];
    }
#pragma unroll
    for (int j = 0; j < VT; ++j) {
      float x = po[j];
#pragma unroll
      for (int off = 32; off >= 1; off >>= 1) x += __shfl_xor(x, off, 64);
      po[j] = x;
    }
    int p = t & 1;
    if (lane == 0) {
#pragma unroll
      for (int j = 0; j < VT; ++j) red[p][wv][j] = po[j];
    }
    __syncthreads();
    if (kt < VT) {
      float s = red[p][0][kt] + red[p][1][kt] + red[p][2][kt] + red[p][3][kt];
      att[base * Vv + v0 + kt] = f2b(s);
    }
  }
  float* so = state_out + ((size_t)b * Kk + kt) * Vv + v0;
#pragma unroll
  for (int j = 0; j < VT; ++j) so[j] = st[j];
}

extern "C" void kernel_launch(void* const* d_in, const int* in_sizes, int n_in,
                              void* d_out, int out_size, void* d_ws, size_t ws_size,
                              hipStream_t stream) {
  const float* hs = (const float*)d_in[0];
  const float* Wq = (const float*)d_in[1];
  const float* bq = (const float*)d_in[2];
  const float* Wk = (const float*)d_in[3];
  const float* bk = (const float*)d_in[4];
  const float* Wv = (const float*)d_in[5];
  const float* bv = (const float*)d_in[6];
  const float* Wg = (const float*)d_in[7];
  const float* bg = (const float*)d_in[8];
  const float* Wo = (const float*)d_in[9];
  const float* bo = (const float*)d_in[10];

  float* out = (float*)d_out;
  float* state_out = out + (size_t)Bb * Tt * Oo;

  char* ws = (char*)d_ws;
  unsigned short* hsb = (unsigned short*)ws;                 // 16384*1024 bf16
  unsigned short* WqT = (unsigned short*)(ws + 33554432);    // each 256*1024 bf16
  unsigned short* WkT = WqT + 262144;
  unsigned short* WgT = WkT + 262144;
  unsigned short* WvT = WgT + 262144;
  unsigned short* WoT = WvT + 262144;                        // 1024*256 bf16
  unsigned short* qb  = WoT + 262144;                        // each 16384*256 bf16
  unsigned short* kb  = qb + 4194304;
  unsigned short* gb  = kb + 4194304;
  unsigned short* vb  = gb + 4194304;
  unsigned short* attb = vb + 4194304;
  // total ws use: 78,118,912 bytes

  // 1) casts
  int n4 = Bb * Tt * Hh / 4;
  cast_bf16_kernel<<<(n4 + 255) / 256, 256, 0, stream>>>(hs, hsb, n4);
  transpose_cast_kernel<<<dim3(Hh / 32, Kk / 32), 256, 0, stream>>>(Wq, WqT, Hh, Kk);
  transpose_cast_kernel<<<dim3(Hh / 32, Kk / 32), 256, 0, stream>>>(Wk, WkT, Hh, Kk);
  transpose_cast_kernel<<<dim3(Hh / 32, Kk / 32), 256, 0, stream>>>(Wg, WgT, Hh, Kk);
  transpose_cast_kernel<<<dim3(Hh / 32, Kk / 32), 256, 0, stream>>>(Wv, WvT, Hh, Kk);
  transpose_cast_kernel<<<dim3(Vv / 32, Oo / 32), 256, 0, stream>>>(Wo, WoT, Vv, Oo);

  // 2) projections (bf16 out; sigmoid on k,g)
  dim3 gp(Kk / BN, (Bb * Tt) / BM);  // (2, 128)
  gemm_bt_kernel<<<gp, 256, 0, stream>>>(hsb, WqT, bq, nullptr, qb, Bb * Tt, Kk, Hh, 1);
  gemm_bt_kernel<<<gp, 256, 0, stream>>>(hsb, WkT, bk, nullptr, kb, Bb * Tt, Kk, Hh, 2);
  gemm_bt_kernel<<<gp, 256, 0, stream>>>(hsb, WgT, bg, nullptr, gb, Bb * Tt, Kk, Hh, 2);
  gemm_bt_kernel<<<gp, 256, 0, stream>>>(hsb, WvT, bv, nullptr, vb, Bb * Tt, Vv, Hh, 1);

  // 3) gated scan
  scan_kernel<<<dim3(Vv / VT, Bb), 256, 0, stream>>>(qb, kb, gb, vb, attb, state_out);

  // 4) output projection (f32 out to d_out)
  dim3 go(Oo / BN, (Bb * Tt) / BM);  // (8, 128)
  gemm_bt_kernel<<<go, 256, 0, stream>>>(attb, WoT, bo, out, nullptr, Bb * Tt, Oo, Vv, 0);
}

// Round 2
// 391.405 us; speedup vs baseline: 5.2809x; 5.2809x over previous
//
#include <hip/hip_runtime.h>

// Problem dims (fixed by setup_inputs)
#define Bb 8
#define Tt 2048
#define Hh 1024
#define Kk 256
#define Vv 256
#define Oo 1024
#define CC 64   // chunk length
#define NC 32   // chunks per batch (Tt/CC)

typedef __attribute__((ext_vector_type(8))) __bf16 bf16x8;
typedef __attribute__((ext_vector_type(4))) float f32x4;

__device__ __forceinline__ unsigned short f2b(float f) {
  unsigned u = __float_as_uint(f);
  u = (u + 0x7FFFu + ((u >> 16) & 1u)) >> 16;
  return (unsigned short)u;
}
__device__ __forceinline__ float b2f(unsigned short u) {
  return __uint_as_float(((unsigned)u) << 16);
}

// ---------------- cast f32 -> bf16 (vectorized) ----------------
__global__ __launch_bounds__(256) void cast_bf16_kernel(const float* __restrict__ in,
                                                        unsigned short* __restrict__ out,
                                                        int n4) {
  int i = blockIdx.x * 256 + threadIdx.x;
  if (i >= n4) return;
  float4 v = ((const float4*)in)[i];
  ushort4 o;
  o.x = f2b(v.x); o.y = f2b(v.y); o.z = f2b(v.z); o.w = f2b(v.w);
  ((ushort4*)out)[i] = o;
}

// ---------------- transpose + cast: W (H x N) f32 -> WT (N x H) bf16 ----------------
__global__ __launch_bounds__(256) void transpose_cast_kernel(const float* __restrict__ W,
                                                             unsigned short* __restrict__ WT,
                                                             int H, int N) {
  __shared__ float tile[32][33];
  int h0 = blockIdx.x * 32, n0 = blockIdx.y * 32;
  int tx = threadIdx.x & 31, ty = threadIdx.x >> 5;
  for (int r = ty; r < 32; r += 8)
    tile[r][tx] = W[(size_t)(h0 + r) * N + n0 + tx];
  __syncthreads();
  for (int r = ty; r < 32; r += 8)
    WT[(size_t)(n0 + r) * H + h0 + tx] = f2b(tile[tx][r]);
}

// ---------------- batched bf16 transpose: in (R x C) -> out (C x R), z = matrix idx ----
__global__ __launch_bounds__(256) void transpose_b16_kernel(
    const unsigned short* __restrict__ in, unsigned short* __restrict__ out,
    int R, int C) {
  __shared__ unsigned short tile[32][33];
  const int r0 = blockIdx.x * 32, c0 = blockIdx.y * 32;
  const size_t base = (size_t)blockIdx.z * R * C;
  const int tx = threadIdx.x & 31, ty = threadIdx.x >> 5;
  for (int rr = ty; rr < 32; rr += 8)
    tile[rr][tx] = in[base + (size_t)(r0 + rr) * C + c0 + tx];
  __syncthreads();
  for (int rr = ty; rr < 32; rr += 8)
    out[base + (size_t)(c0 + rr) * R + r0 + tx] = tile[tx][rr];
}

// ---------------- bf16 MFMA GEMM: C = A (MxK) * Bt^T (Bt is NxK) + bias ----------------
// mode 0: f32 out, 1: bf16 out, 2: bf16 out + sigmoid, 5: f16 out = log2(sigmoid(x))
#define BM 128
#define BN 128
#define BKK 32

__global__ __launch_bounds__(256) void gemm_bt_kernel(
    const unsigned short* __restrict__ A,
    const unsigned short* __restrict__ Bt,
    const float* __restrict__ bias,
    float* __restrict__ Cf,
    unsigned short* __restrict__ Cb,
    int M, int N, int K, int mode) {
  __shared__ __align__(16) unsigned short As[BM][40];
  __shared__ __align__(16) unsigned short Bs[BN][40];
  const int tid = threadIdx.x;
  const int lane = tid & 63, wid = tid >> 6;
  const int wm = wid >> 1, wn = wid & 1;
  const int m0 = blockIdx.y * BM, n0 = blockIdx.x * BN;
  const int sr = tid >> 1, sc = (tid & 1) * 16;
  const int fr = lane & 15, fk = (lane >> 4) * 8;
  f32x4 acc[4][4] = {};
  for (int k0 = 0; k0 < K; k0 += BKK) {
    const unsigned short* ap = A + (size_t)(m0 + sr) * K + k0 + sc;
    const unsigned short* bp = Bt + (size_t)(n0 + sr) * K + k0 + sc;
    uint4 a0 = *(const uint4*)ap;
    uint4 a1 = *(const uint4*)(ap + 8);
    uint4 b0 = *(const uint4*)bp;
    uint4 b1 = *(const uint4*)(bp + 8);
    __syncthreads();
    *(uint4*)&As[sr][sc] = a0;
    *(uint4*)&As[sr][sc + 8] = a1;
    *(uint4*)&Bs[sr][sc] = b0;
    *(uint4*)&Bs[sr][sc + 8] = b1;
    __syncthreads();
    bf16x8 af[4], bfv[4];
#pragma unroll
    for (int i = 0; i < 4; ++i)
      af[i] = *(const bf16x8*)&As[wm * 64 + i * 16 + fr][fk];
#pragma unroll
    for (int i = 0; i < 4; ++i)
      bfv[i] = *(const bf16x8*)&Bs[wn * 64 + i * 16 + fr][fk];
#pragma unroll
    for (int i = 0; i < 4; ++i)
#pragma unroll
      for (int j = 0; j < 4; ++j)
        acc[i][j] = __builtin_amdgcn_mfma_f32_16x16x32_bf16(af[i], bfv[j], acc[i][j], 0, 0, 0);
  }
  const int fq = lane >> 4;
#pragma unroll
  for (int j = 0; j < 4; ++j) {
    int n = n0 + wn * 64 + j * 16 + fr;
    float bv = bias[n];
#pragma unroll
    for (int i = 0; i < 4; ++i) {
      int mb = m0 + wm * 64 + i * 16 + fq * 4;
#pragma unroll
      for (int r = 0; r < 4; ++r) {
        float x = acc[i][j][r] + bv;
        size_t idx = (size_t)(mb + r) * N + n;
        if (mode == 0) {
          Cf[idx] = x;
        } else if (mode == 1) {
          Cb[idx] = f2b(x);
        } else if (mode == 2) {
          Cb[idx] = f2b(1.f / (1.f + expf(-x)));
        } else {  // mode 5: log2(sigmoid(x)) as f16
          float e = exp2f(-x * 1.44269504f);
          float lg = -log2f(1.f + e);
          _Float16 hv = (_Float16)lg;
          unsigned short u;
          __builtin_memcpy(&u, &hv, 2);
          Cb[idx] = u;
        }
      }
    }
  }
}

// ---------------- prep: per (b,c) compute L cumsums & scaled q/k variants ----------------
// thread = k channel (256). Outputs:
//  q2 = q*2^L ; qa = q*2^(L-LB_I) ; ka = k*2^(LB_I-L) ; khT[k][s] = k*2^(Lend-L)
//  LB[task][I][k] (f32), Dend[task][k] = 2^Lend (f32)
__global__ __launch_bounds__(256) void prep_kernel(
    const unsigned short* __restrict__ qb, const unsigned short* __restrict__ kb,
    const unsigned short* __restrict__ lgb,
    unsigned short* __restrict__ q2b, unsigned short* __restrict__ qab,
    unsigned short* __restrict__ kab, unsigned short* __restrict__ khTb,
    float* __restrict__ LBb, float* __restrict__ Dendb) {
  const int c = blockIdx.x, b = blockIdx.y;
  const int k = threadIdx.x;
  const int task = b * NC + c;
  const size_t rowbase = ((size_t)b * Tt + (size_t)c * CC) * Kk + k;
  // pass 1: total log-sum + block bases
  float Ls = 0.f;
  float LBr[4];
#pragma unroll
  for (int gq = 0; gq < 4; ++gq) {
    LBr[gq] = Ls;
#pragma unroll
    for (int tt = 0; tt < 16; ++tt) {
      int t = gq * 16 + tt;
      _Float16 hv;
      __builtin_memcpy(&hv, &lgb[rowbase + (size_t)t * Kk], 2);
      Ls += (float)hv;
    }
  }
  const float Lend = Ls;
#pragma unroll
  for (int gq = 0; gq < 4; ++gq) LBb[(size_t)task * 1024 + gq * 256 + k] = LBr[gq];
  Dendb[task * 256 + k] = exp2f(Lend);
  // pass 2: emit scaled tensors
  float L = 0.f;
#pragma unroll
  for (int gq = 0; gq < 4; ++gq) {
    const float LBc = LBr[gq];
    unsigned kw[8];
#pragma unroll
    for (int tt = 0; tt < 16; ++tt) {
      int t = gq * 16 + tt;
      size_t off = rowbase + (size_t)t * Kk;
      _Float16 hv;
      __builtin_memcpy(&hv, &lgb[off], 2);
      L += (float)hv;
      float qv = b2f(qb[off]);
      float kv = b2f(kb[off]);
      q2b[off] = f2b(qv * exp2f(L));
      qab[off] = f2b(qv * exp2f(L - LBc));
      kab[off] = f2b(kv * exp2f(LBc - L));
      unsigned short kh = f2b(kv * exp2f(Lend - L));
      if (tt & 1) kw[tt >> 1] |= ((unsigned)kh) << 16;
      else        kw[tt >> 1] = kh;
    }
    unsigned short* dst = khTb + (size_t)task * (Kk * CC) + (size_t)k * CC + gq * 16;
    uint4 u0; u0.x = kw[0]; u0.y = kw[1]; u0.z = kw[2]; u0.w = kw[3];
    uint4 u1; u1.x = kw[4]; u1.y = kw[5]; u1.z = kw[6]; u1.w = kw[7];
    *(uint4*)dst = u0;
    *(uint4*)(dst + 8) = u1;
  }
}

// ---------------- sgemm: S[task][k][v] = sum_s khT[k][s] * vT[v][s] ----------------
__global__ __launch_bounds__(256) void sgemm_kernel(
    const unsigned short* __restrict__ khTb, const unsigned short* __restrict__ vTb,
    unsigned short* __restrict__ Sb) {
  const int c = blockIdx.x, b = blockIdx.y;
  const int task = b * NC + c;
  const int tid = threadIdx.x, lane = tid & 63, w = tid >> 6;
  const int fr = lane & 15, fq = lane >> 4, fk = fq * 8;
  const unsigned short* kt = khTb + (size_t)task * (Kk * CC);
  const unsigned short* vt = vTb + (size_t)b * (Vv * Tt) + (size_t)c * CC;
  for (int vb4 = 0; vb4 < 4; ++vb4) {
    f32x4 acc[4][4] = {};
#pragma unroll
    for (int ks = 0; ks < 2; ++ks) {
      bf16x8 af[4], bf[4];
#pragma unroll
      for (int i = 0; i < 4; ++i)
        af[i] = *(const bf16x8*)(kt + (size_t)(w * 64 + i * 16 + fr) * CC + ks * 32 + fk);
#pragma unroll
      for (int j = 0; j < 4; ++j)
        bf[j] = *(const bf16x8*)(vt + (size_t)(vb4 * 64 + j * 16 + fr) * Tt + ks * 32 + fk);
#pragma unroll
      for (int i = 0; i < 4; ++i)
#pragma unroll
        for (int j = 0; j < 4; ++j)
          acc[i][j] = __builtin_amdgcn_mfma_f32_16x16x32_bf16(af[i], bf[j], acc[i][j], 0, 0, 0);
    }
#pragma unroll
    for (int i = 0; i < 4; ++i)
#pragma unroll
      for (int j = 0; j < 4; ++j)
#pragma unroll
        for (int r = 0; r < 4; ++r)
          Sb[(size_t)task * (Kk * Vv) + (size_t)(w * 64 + i * 16 + fq * 4 + r) * Vv +
             vb4 * 64 + j * 16 + fr] = f2b(acc[i][j][r]);
  }
}

// ---------------- passR: sequential chunk recombine (parallel over B,K,V) ----------------
// writes S0T[task][v][k] (bf16, pre-chunk state, transposed) and final state (f32)
__global__ __launch_bounds__(256) void passR_kernel(
    const unsigned short* __restrict__ Sb, const float* __restrict__ Dendb,
    unsigned short* __restrict__ S0Tb, float* __restrict__ state_out) {
  const int vt = blockIdx.x, kt = blockIdx.y, b = blockIdx.z;
  const int tid = threadIdx.x;
  const int kq = tid >> 2;   // k_local 0..63
  const int vq = tid & 3;    // v group (16 v each)
  const int vr = tid >> 2;   // write-phase: v row
  const int kqq = tid & 3;   // write-phase: k group
  __shared__ __align__(16) unsigned short Ts[64][72];
  float st[16];
#pragma unroll
  for (int j = 0; j < 16; ++j) st[j] = 0.f;
  for (int c = 0; c < NC; ++c) {
    const int task = b * NC + c;
    // stage pre-state (transposed) to LDS, then write S0T
#pragma unroll
    for (int j = 0; j < 16; ++j) Ts[vq * 16 + j][kq] = f2b(st[j]);
    __syncthreads();
    {
      unsigned short* dst = S0Tb + (size_t)task * (Kk * Vv) +
                            (size_t)(vt * 64 + vr) * Kk + kt * 64 + kqq * 16;
      *(uint4*)dst = *(const uint4*)&Ts[vr][kqq * 16];
      *(uint4*)(dst + 8) = *(const uint4*)&Ts[vr][kqq * 16 + 8];
    }
    __syncthreads();
    // update: st = Dend * st + S
    const float d = Dendb[task * 256 + kt * 64 + kq];
    const unsigned short* sp = Sb + (size_t)task * (Kk * Vv) +
                               (size_t)(kt * 64 + kq) * Vv + vt * 64 + vq * 16;
#pragma unroll
    for (int h = 0; h < 2; ++h) {
      uint4 raw = *(const uint4*)(sp + h * 8);
      unsigned ws_[4] = {raw.x, raw.y, raw.z, raw.w};
#pragma unroll
      for (int e = 0; e < 4; ++e) {
        float lo = __uint_as_float(ws_[e] << 16);
        float hi = __uint_as_float(ws_[e] & 0xFFFF0000u);
        st[h * 8 + e * 2]     = d * st[h * 8 + e * 2] + lo;
        st[h * 8 + e * 2 + 1] = d * st[h * 8 + e * 2 + 1] + hi;
      }
    }
  }
  float* so = state_out + (size_t)(b * Kk + kt * 64 + kq) * Vv + vt * 64 + vq * 16;
#pragma unroll
  for (int j = 0; j < 16; ++j) so[j] = st[j];
}

// ---------------- passO: per (b,c): att = q2*S0 + tril(A)*v ----------------
__global__ __launch_bounds__(256) void passO_kernel(
    const unsigned short* __restrict__ qab, const unsigned short* __restrict__ kab,
    const unsigned short* __restrict__ q2b, const float* __restrict__ LBb,
    const unsigned short* __restrict__ S0Tb, const unsigned short* __restrict__ vTb,
    unsigned short* __restrict__ attb) {
  const int c = blockIdx.x, b = blockIdx.y;
  const int task = b * NC + c;
  const int tid = threadIdx.x, lane = tid & 63, w = tid >> 6;
  const int fr = lane & 15, fq = lane >> 4, fk = fq * 8;
  __shared__ float LB_s[4][256];
  __shared__ __align__(16) unsigned short A_s[64][72];
  const size_t tbase = (size_t)task * (CC * Kk);
  for (int idx = tid; idx < 1024; idx += 256) LB_s[idx >> 8][idx & 255] = LBb[(size_t)task * 1024 + idx];
  for (int idx = tid; idx < 64 * 72 / 2; idx += 256) ((unsigned*)A_s)[idx] = 0;
  __syncthreads();
  // intra: A_IJ = (qa_I * 2^(LB_I - LB_J)) . ka_J^T   for J <= I
  for (int p = w; p < 10; p += 4) {
    const int I = (p >= 6) ? 3 : (p >= 3) ? 2 : (p >= 1) ? 1 : 0;
    const int J = p - (I * (I + 1)) / 2;
    f32x4 acc = {0.f, 0.f, 0.f, 0.f};
#pragma unroll
    for (int ks = 0; ks < 8; ++ks) {
      const int k0 = ks * 32 + fk;
      bf16x8 af = *(const bf16x8*)(qab + tbase + (size_t)(I * 16 + fr) * Kk + k0);
      if (I != J) {
#pragma unroll
        for (int e = 0; e < 8; ++e) {
          float d = exp2f(LB_s[I][k0 + e] - LB_s[J][k0 + e]);
          af[e] = (__bf16)((float)af[e] * d);
        }
      }
      bf16x8 bf = *(const bf16x8*)(kab + tbase + (size_t)(J * 16 + fr) * Kk + k0);
      acc = __builtin_amdgcn_mfma_f32_16x16x32_bf16(af, bf, acc, 0, 0, 0);
    }
#pragma unroll
    for (int r = 0; r < 4; ++r) {
      const int ml = fq * 4 + r, nl = fr;
      bool keep = (I != J) || (nl <= ml);
      A_s[I * 16 + ml][J * 16 + nl] = keep ? f2b(acc[r]) : (unsigned short)0;
    }
  }
  __syncthreads();
  // output: acc2 = q2 . S0T^T  +  A . vT^T
  f32x4 acc2[4][4] = {};
  const unsigned short* q2t = q2b + tbase;
  const unsigned short* s0t = S0Tb + (size_t)task * (Kk * Vv);
  const unsigned short* vtp = vTb + (size_t)b * (Vv * Tt) + (size_t)c * CC;
  const int vbase = w * 64;
#pragma unroll
  for (int ks = 0; ks < 8; ++ks) {
    const int k0 = ks * 32 + fk;
    bf16x8 af[4], bf[4];
#pragma unroll
    for (int i = 0; i < 4; ++i) af[i] = *(const bf16x8*)(q2t + (size_t)(i * 16 + fr) * Kk + k0);
#pragma unroll
    for (int j = 0; j < 4; ++j) bf[j] = *(const bf16x8*)(s0t + (size_t)(vbase + j * 16 + fr) * Kk + k0);
#pragma unroll
    for (int i = 0; i < 4; ++i)
#pragma unroll
      for (int j = 0; j < 4; ++j)
        acc2[i][j] = __builtin_amdgcn_mfma_f32_16x16x32_bf16(af[i], bf[j], acc2[i][j], 0, 0, 0);
  }
#pragma unroll
  for (int ks = 0; ks < 2; ++ks) {
    const int s0 = ks * 32 + fk;
    bf16x8 af[4], bf[4];
#pragma unroll
    for (int i = 0; i < 4; ++i) af[i] = *(const bf16x8*)&A_s[i * 16 + fr][s0];
#pragma unroll
    for (int j = 0; j < 4; ++j) bf[j] = *(const bf16x8*)(vtp + (size_t)(vbase + j * 16 + fr) * Tt + s0);
#pragma unroll
    for (int i = 0; i < 4; ++i)
#pragma unroll
      for (int j = 0; j < 4; ++j)
        acc2[i][j] = __builtin_amdgcn_mfma_f32_16x16x32_bf16(af[i], bf[j], acc2[i][j], 0, 0, 0);
  }
#pragma unroll
  for (int i = 0; i < 4; ++i)
#pragma unroll
    for (int j = 0; j < 4; ++j)
#pragma unroll
      for (int r = 0; r < 4; ++r)
        attb[((size_t)b * Tt + c * CC + i * 16 + fq * 4 + r) * Vv + vbase + j * 16 + fr]
            = f2b(acc2[i][j][r]);
}

extern "C" void kernel_launch(void* const* d_in, const int* in_sizes, int n_in,
                              void* d_out, int out_size, void* d_ws, size_t ws_size,
                              hipStream_t stream) {
  const float* hs = (const float*)d_in[0];
  const float* Wq = (const float*)d_in[1];
  const float* bq = (const float*)d_in[2];
  const float* Wk = (const float*)d_in[3];
  const float* bk = (const float*)d_in[4];
  const float* Wv = (const float*)d_in[5];
  const float* bv = (const float*)d_in[6];
  const float* Wg = (const float*)d_in[7];
  const float* bg = (const float*)d_in[8];
  const float* Wo = (const float*)d_in[9];
  const float* bo = (const float*)d_in[10];

  float* out = (float*)d_out;
  float* state_out = out + (size_t)Bb * Tt * Oo;

  char* p = (char*)d_ws;
  auto alloc = [&](size_t bytes) {
    char* r = p;
    p += (bytes + 255) & ~(size_t)255;
    return r;
  };
  unsigned short* hsb  = (unsigned short*)alloc((size_t)Bb * Tt * Hh * 2);  // 32MB
  unsigned short* WqT  = (unsigned short*)alloc((size_t)Kk * Hh * 2);
  unsigned short* WkT  = (unsigned short*)alloc((size_t)Kk * Hh * 2);
  unsigned short* WgT  = (unsigned short*)alloc((size_t)Kk * Hh * 2);
  unsigned short* WvT  = (unsigned short*)alloc((size_t)Vv * Hh * 2);
  unsigned short* WoT  = (unsigned short*)alloc((size_t)Oo * Vv * 2);
  unsigned short* qb   = (unsigned short*)alloc((size_t)Bb * Tt * Kk * 2);  // 8MB each
  unsigned short* kb   = (unsigned short*)alloc((size_t)Bb * Tt * Kk * 2);
  unsigned short* vb   = (unsigned short*)alloc((size_t)Bb * Tt * Vv * 2);
  unsigned short* lgb  = (unsigned short*)alloc((size_t)Bb * Tt * Kk * 2);  // f16
  unsigned short* attb = (unsigned short*)alloc((size_t)Bb * Tt * Vv * 2);
  unsigned short* q2b  = (unsigned short*)alloc((size_t)Bb * Tt * Kk * 2);
  unsigned short* qab  = (unsigned short*)alloc((size_t)Bb * Tt * Kk * 2);
  unsigned short* kab  = (unsigned short*)alloc((size_t)Bb * Tt * Kk * 2);
  unsigned short* khTb = (unsigned short*)alloc((size_t)Bb * NC * Kk * CC * 2);
  unsigned short* vTb  = (unsigned short*)alloc((size_t)Bb * Vv * Tt * 2);
  float*          LBb  = (float*)alloc((size_t)Bb * NC * 4 * Kk * 4);       // 1MB
  float*          Dendb= (float*)alloc((size_t)Bb * NC * Kk * 4);           // 256KB
  unsigned short* Sb   = (unsigned short*)alloc((size_t)Bb * NC * Kk * Vv * 2);  // 32MB
  unsigned short* S0Tb = (unsigned short*)alloc((size_t)Bb * NC * Kk * Vv * 2);  // 32MB

  // 1) casts
  int n4 = Bb * Tt * Hh / 4;
  cast_bf16_kernel<<<(n4 + 255) / 256, 256, 0, stream>>>(hs, hsb, n4);
  transpose_cast_kernel<<<dim3(Hh / 32, Kk / 32), 256, 0, stream>>>(Wq, WqT, Hh, Kk);
  transpose_cast_kernel<<<dim3(Hh / 32, Kk / 32), 256, 0, stream>>>(Wk, WkT, Hh, Kk);
  transpose_cast_kernel<<<dim3(Hh / 32, Kk / 32), 256, 0, stream>>>(Wg, WgT, Hh, Kk);
  transpose_cast_kernel<<<dim3(Hh / 32, Kk / 32), 256, 0, stream>>>(Wv, WvT, Hh, Kk);
  transpose_cast_kernel<<<dim3(Vv / 32, Oo / 32), 256, 0, stream>>>(Wo, WoT, Vv, Oo);

  // 2) projections: q (bf16), k (sigmoid bf16), g (log2-sigmoid f16), v (bf16)
  dim3 gp(Kk / BN, (Bb * Tt) / BM);
  gemm_bt_kernel<<<gp, 256, 0, stream>>>(hsb, WqT, bq, nullptr, qb, Bb * Tt, Kk, Hh, 1);
  gemm_bt_kernel<<<gp, 256, 0, stream>>>(hsb, WkT, bk, nullptr, kb, Bb * Tt, Kk, Hh, 2);
  gemm_bt_kernel<<<gp, 256, 0, stream>>>(hsb, WgT, bg, nullptr, lgb, Bb * Tt, Kk, Hh, 5);
  gemm_bt_kernel<<<gp, 256, 0, stream>>>(hsb, WvT, bv, nullptr, vb, Bb * Tt, Vv, Hh, 1);

  // 3) vT: per-batch transpose (T x V -> V x T)
  transpose_b16_kernel<<<dim3(Tt / 32, Vv / 32, Bb), 256, 0, stream>>>(vb, vTb, Tt, Vv);

  // 4) prep (L cumsums, scaled tensors)
  prep_kernel<<<dim3(NC, Bb), 256, 0, stream>>>(qb, kb, lgb, q2b, qab, kab, khTb, LBb, Dendb);

  // 5) per-chunk state contribution S = khT . vT^T
  sgemm_kernel<<<dim3(NC, Bb), 256, 0, stream>>>(khTb, vTb, Sb);

  // 6) sequential chunk recombine -> S0T (pre-chunk states) + final state
  passR_kernel<<<dim3(Vv / 64, Kk / 64, Bb), 256, 0, stream>>>(Sb, Dendb, S0Tb, state_out);

  // 7) outputs: att = q2.S0 + tril(A).v
  passO_kernel<<<dim3(NC, Bb), 256, 0, stream>>>(qab, kab, q2b, LBb, S0Tb, vTb, attb);

  // 8) output projection
  dim3 go(Oo / BN, (Bb * Tt) / BM);
  gemm_bt_kernel<<<go, 256, 0, stream>>>(attb, WoT, bo, out, nullptr, Bb * Tt, Oo, Vv, 0);
}

// Round 3
// 308.615 us; speedup vs baseline: 6.6976x; 1.2683x over previous
//
#include <hip/hip_runtime.h>

// Problem dims (fixed by setup_inputs)
#define Bb 8
#define Tt 2048
#define Hh 1024
#define Kk 256
#define Vv 256
#define Oo 1024
#define CC 64   // chunk length
#define NC 32   // chunks per batch (Tt/CC)

typedef __attribute__((ext_vector_type(8))) __bf16 bf16x8;
typedef __attribute__((ext_vector_type(4))) float f32x4;

__device__ __forceinline__ unsigned short f2b(float f) {
  unsigned u = __float_as_uint(f);
  u = (u + 0x7FFFu + ((u >> 16) & 1u)) >> 16;
  return (unsigned short)u;
}
__device__ __forceinline__ float b2f(unsigned short u) {
  return __uint_as_float(((unsigned)u) << 16);
}
__device__ __forceinline__ void gload_lds16(const unsigned short* g, unsigned short* l) {
  __builtin_amdgcn_global_load_lds(
      (const __attribute__((address_space(1))) void*)g,
      (__attribute__((address_space(3))) void*)l, 16, 0, 0);
}

// ---------------- cast f32 -> bf16 (vectorized) ----------------
__global__ __launch_bounds__(256) void cast_bf16_kernel(const float* __restrict__ in,
                                                        unsigned short* __restrict__ out,
                                                        int n4) {
  int i = blockIdx.x * 256 + threadIdx.x;
  if (i >= n4) return;
  float4 v = ((const float4*)in)[i];
  ushort4 o;
  o.x = f2b(v.x); o.y = f2b(v.y); o.z = f2b(v.z); o.w = f2b(v.w);
  ((ushort4*)out)[i] = o;
}

// ---------------- transpose + cast: W (H x N) f32 -> WT (N x H) bf16 ----------------
__global__ __launch_bounds__(256) void transpose_cast_kernel(const float* __restrict__ W,
                                                             unsigned short* __restrict__ WT,
                                                             int H, int N) {
  __shared__ float tile[32][33];
  int h0 = blockIdx.x * 32, n0 = blockIdx.y * 32;
  int tx = threadIdx.x & 31, ty = threadIdx.x >> 5;
  for (int r = ty; r < 32; r += 8)
    tile[r][tx] = W[(size_t)(h0 + r) * N + n0 + tx];
  __syncthreads();
  for (int r = ty; r < 32; r += 8)
    WT[(size_t)(n0 + r) * H + h0 + tx] = f2b(tile[tx][r]);
}

// ---------------- m97-style MFMA GEMM, global_load_lds staging ----------------
// C = A (MxK, bf16 row-major) * Bt^T (Bt NxK bf16 row-major)
// MODE 0: fused projection epilogue: n>>8 selects {q, sigmoid->k, log2sig->g(f16), v->vT}
// MODE 1: f32 out with bias b0p
#define BM 128
#define BN 128
#define BK 32

template <int MODE>
__global__ __launch_bounds__(256) void gemm_fused_kernel(
    const unsigned short* __restrict__ A, const unsigned short* __restrict__ Bt,
    const float* __restrict__ b0p, const float* __restrict__ b1p,
    const float* __restrict__ b2p, const float* __restrict__ b3p,
    float* __restrict__ Cf,
    unsigned short* __restrict__ O0, unsigned short* __restrict__ O1,
    unsigned short* __restrict__ O2, unsigned short* __restrict__ O3,
    int M, int N, int K) {
  __shared__ __align__(16) unsigned short As[BM * BK];
  __shared__ __align__(16) unsigned short Bs[BN * BK];
  const int tid = threadIdx.x;
  const int lane = tid & 63, wid = tid >> 6;
  const int wm = wid >> 1, wn = wid & 1;
  // XCD-aware bijective swizzle (nwg divisible by 8)
  const int nxt = gridDim.x;
  const int lin = blockIdx.x + blockIdx.y * nxt;
  const int cpx = (nxt * gridDim.y) >> 3;
  const int swz = (lin & 7) * cpx + (lin >> 3);
  const int m0 = (swz / nxt) * BM, n0 = (swz % nxt) * BN;
  const int fr = lane & 15, fq = lane >> 4, fk = fq * 8;
  // staging map: wave wid covers rows [32*wid, 32*wid+32) of each tile
  const int srow = 32 * wid + (lane >> 2);
  const int scol = (lane & 3) * 8;
  f32x4 acc[4][4] = {};
  for (int k0 = 0; k0 < K; k0 += BK) {
    __syncthreads();
    const unsigned short* ga = A + (size_t)(m0 + srow) * K + k0 + scol;
    const unsigned short* gb = Bt + (size_t)(n0 + srow) * K + k0 + scol;
    gload_lds16(ga, &As[(32 * wid) * BK]);
    gload_lds16(ga + 16 * (size_t)K, &As[(32 * wid + 16) * BK]);
    gload_lds16(gb, &Bs[(32 * wid) * BK]);
    gload_lds16(gb + 16 * (size_t)K, &Bs[(32 * wid + 16) * BK]);
    __syncthreads();
    bf16x8 af[4], bfv[4];
#pragma unroll
    for (int i = 0; i < 4; ++i)
      af[i] = *(const bf16x8*)&As[(wm * 64 + i * 16 + fr) * BK + fk];
#pragma unroll
    for (int i = 0; i < 4; ++i)
      bfv[i] = *(const bf16x8*)&Bs[(wn * 64 + i * 16 + fr) * BK + fk];
#pragma unroll
    for (int i = 0; i < 4; ++i)
#pragma unroll
      for (int j = 0; j < 4; ++j)
        acc[i][j] = __builtin_amdgcn_mfma_f32_16x16x32_bf16(af[i], bfv[j], acc[i][j], 0, 0, 0);
  }
#pragma unroll
  for (int j = 0; j < 4; ++j) {
    const int n = n0 + wn * 64 + j * 16 + fr;
    if (MODE == 1) {
      const float bv = b0p[n];
#pragma unroll
      for (int i = 0; i < 4; ++i) {
        const int mb = m0 + wm * 64 + i * 16 + fq * 4;
#pragma unroll
        for (int r = 0; r < 4; ++r)
          Cf[(size_t)(mb + r) * N + n] = acc[i][j][r] + bv;
      }
    } else {
      const int sel = n >> 8, nl = n & 255;
      const float bv = sel == 0 ? b0p[nl] : sel == 1 ? b1p[nl] : sel == 2 ? b2p[nl] : b3p[nl];
#pragma unroll
      for (int i = 0; i < 4; ++i) {
        const int mb = m0 + wm * 64 + i * 16 + fq * 4;
#pragma unroll
        for (int r = 0; r < 4; ++r) {
          const int m = mb + r;
          const float x = acc[i][j][r] + bv;
          if (sel == 0) {
            O0[(size_t)m * Kk + nl] = f2b(x);
          } else if (sel == 1) {
            O1[(size_t)m * Kk + nl] = f2b(1.f / (1.f + expf(-x)));
          } else if (sel == 2) {
            float e = exp2f(-x * 1.44269504f);
            float lg = -log2f(1.f + e);
            _Float16 hv = (_Float16)lg;
            unsigned short u;
            __builtin_memcpy(&u, &hv, 2);
            O2[(size_t)m * Kk + nl] = u;
          } else {  // v -> transposed vT[b][v][t]
            O3[((size_t)(m >> 11) * Vv + nl) * Tt + (m & 2047)] = f2b(x);
          }
        }
      }
    }
  }
}

// ---------------- prep: per (b,c) compute L cumsums & scaled q/k variants ----------------
__global__ __launch_bounds__(256) void prep_kernel(
    const unsigned short* __restrict__ qb, const unsigned short* __restrict__ kb,
    const unsigned short* __restrict__ lgb,
    unsigned short* __restrict__ q2b, unsigned short* __restrict__ qab,
    unsigned short* __restrict__ kab, unsigned short* __restrict__ khTb,
    float* __restrict__ LBb, float* __restrict__ Dendb) {
  const int c = blockIdx.x, b = blockIdx.y;
  const int k = threadIdx.x;
  const int task = b * NC + c;
  const size_t rowbase = ((size_t)b * Tt + (size_t)c * CC) * Kk + k;
  float Ls = 0.f;
  float LBr[4];
#pragma unroll
  for (int gq = 0; gq < 4; ++gq) {
    LBr[gq] = Ls;
#pragma unroll
    for (int tt = 0; tt < 16; ++tt) {
      int t = gq * 16 + tt;
      _Float16 hv;
      __builtin_memcpy(&hv, &lgb[rowbase + (size_t)t * Kk], 2);
      Ls += (float)hv;
    }
  }
  const float Lend = Ls;
#pragma unroll
  for (int gq = 0; gq < 4; ++gq) LBb[(size_t)task * 1024 + gq * 256 + k] = LBr[gq];
  Dendb[task * 256 + k] = exp2f(Lend);
  float L = 0.f;
#pragma unroll
  for (int gq = 0; gq < 4; ++gq) {
    const float LBc = LBr[gq];
    unsigned kw[8];
#pragma unroll
    for (int tt = 0; tt < 16; ++tt) {
      int t = gq * 16 + tt;
      size_t off = rowbase + (size_t)t * Kk;
      _Float16 hv;
      __builtin_memcpy(&hv, &lgb[off], 2);
      L += (float)hv;
      float qv = b2f(qb[off]);
      float kv = b2f(kb[off]);
      q2b[off] = f2b(qv * exp2f(L));
      qab[off] = f2b(qv * exp2f(L - LBc));
      kab[off] = f2b(kv * exp2f(LBc - L));
      unsigned short kh = f2b(kv * exp2f(Lend - L));
      if (tt & 1) kw[tt >> 1] |= ((unsigned)kh) << 16;
      else        kw[tt >> 1] = kh;
    }
    unsigned short* dst = khTb + (size_t)task * (Kk * CC) + (size_t)k * CC + gq * 16;
    uint4 u0; u0.x = kw[0]; u0.y = kw[1]; u0.z = kw[2]; u0.w = kw[3];
    uint4 u1; u1.x = kw[4]; u1.y = kw[5]; u1.z = kw[6]; u1.w = kw[7];
    *(uint4*)dst = u0;
    *(uint4*)(dst + 8) = u1;
  }
}

// ---------------- sgemm: S[task][k][v] = sum_s khT[k][s] * vT[v][s] ----------------
__global__ __launch_bounds__(256) void sgemm_kernel(
    const unsigned short* __restrict__ khTb, const unsigned short* __restrict__ vTb,
    unsigned short* __restrict__ Sb) {
  const int c = blockIdx.x, b = blockIdx.y;
  const int task = b * NC + c;
  const int tid = threadIdx.x, lane = tid & 63, w = tid >> 6;
  const int fr = lane & 15, fq = lane >> 4, fk = fq * 8;
  const unsigned short* kt = khTb + (size_t)task * (Kk * CC);
  const unsigned short* vt = vTb + (size_t)b * (Vv * Tt) + (size_t)c * CC;
  for (int vb4 = 0; vb4 < 4; ++vb4) {
    f32x4 acc[4][4] = {};
#pragma unroll
    for (int ks = 0; ks < 2; ++ks) {
      bf16x8 af[4], bf[4];
#pragma unroll
      for (int i = 0; i < 4; ++i)
        af[i] = *(const bf16x8*)(kt + (size_t)(w * 64 + i * 16 + fr) * CC + ks * 32 + fk);
#pragma unroll
      for (int j = 0; j < 4; ++j)
        bf[j] = *(const bf16x8*)(vt + (size_t)(vb4 * 64 + j * 16 + fr) * Tt + ks * 32 + fk);
#pragma unroll
      for (int i = 0; i < 4; ++i)
#pragma unroll
        for (int j = 0; j < 4; ++j)
          acc[i][j] = __builtin_amdgcn_mfma_f32_16x16x32_bf16(af[i], bf[j], acc[i][j], 0, 0, 0);
    }
#pragma unroll
    for (int i = 0; i < 4; ++i)
#pragma unroll
      for (int j = 0; j < 4; ++j)
#pragma unroll
        for (int r = 0; r < 4; ++r)
          Sb[(size_t)task * (Kk * Vv) + (size_t)(w * 64 + i * 16 + fq * 4 + r) * Vv +
             vb4 * 64 + j * 16 + fr] = f2b(acc[i][j][r]);
  }
}

// ---------------- passR: sequential chunk recombine (parallel over B,K,V) ----------------
__global__ __launch_bounds__(256) void passR_kernel(
    const unsigned short* __restrict__ Sb, const float* __restrict__ Dendb,
    unsigned short* __restrict__ S0Tb, float* __restrict__ state_out) {
  const int vt = blockIdx.x, kt = blockIdx.y, b = blockIdx.z;
  const int tid = threadIdx.x;
  const int kq = tid >> 2;
  const int vq = tid & 3;
  const int vr = tid >> 2;
  const int kqq = tid & 3;
  __shared__ __align__(16) unsigned short Ts[64][72];
  float st[16];
#pragma unroll
  for (int j = 0; j < 16; ++j) st[j] = 0.f;
  for (int c = 0; c < NC; ++c) {
    const int task = b * NC + c;
#pragma unroll
    for (int j = 0; j < 16; ++j) Ts[vq * 16 + j][kq] = f2b(st[j]);
    __syncthreads();
    {
      unsigned short* dst = S0Tb + (size_t)task * (Kk * Vv) +
                            (size_t)(vt * 64 + vr) * Kk + kt * 64 + kqq * 16;
      *(uint4*)dst = *(const uint4*)&Ts[vr][kqq * 16];
      *(uint4*)(dst + 8) = *(const uint4*)&Ts[vr][kqq * 16 + 8];
    }
    __syncthreads();
    const float d = Dendb[task * 256 + kt * 64 + kq];
    const unsigned short* sp = Sb + (size_t)task * (Kk * Vv) +
                               (size_t)(kt * 64 + kq) * Vv + vt * 64 + vq * 16;
#pragma unroll
    for (int h = 0; h < 2; ++h) {
      uint4 raw = *(const uint4*)(sp + h * 8);
      unsigned ws_[4] = {raw.x, raw.y, raw.z, raw.w};
#pragma unroll
      for (int e = 0; e < 4; ++e) {
        float lo = __uint_as_float(ws_[e] << 16);
        float hi = __uint_as_float(ws_[e] & 0xFFFF0000u);
        st[h * 8 + e * 2]     = d * st[h * 8 + e * 2] + lo;
        st[h * 8 + e * 2 + 1] = d * st[h * 8 + e * 2 + 1] + hi;
      }
    }
  }
  float* so = state_out + (size_t)(b * Kk + kt * 64 + kq) * Vv + vt * 64 + vq * 16;
#pragma unroll
  for (int j = 0; j < 16; ++j) so[j] = st[j];
}

// ---------------- passO: per (b,c): att = q2*S0 + tril(A)*v ----------------
__global__ __launch_bounds__(256) void passO_kernel(
    const unsigned short* __restrict__ qab, const unsigned short* __restrict__ kab,
    const unsigned short* __restrict__ q2b, const float* __restrict__ LBb,
    const unsigned short* __restrict__ S0Tb, const unsigned short* __restrict__ vTb,
    unsigned short* __restrict__ attb) {
  const int c = blockIdx.x, b = blockIdx.y;
  const int task = b * NC + c;
  const int tid = threadIdx.x, lane = tid & 63, w = tid >> 6;
  const int fr = lane & 15, fq = lane >> 4, fk = fq * 8;
  __shared__ float LB_s[4][256];
  __shared__ __align__(16) unsigned short A_s[64][72];
  const size_t tbase = (size_t)task * (CC * Kk);
  for (int idx = tid; idx < 1024; idx += 256) LB_s[idx >> 8][idx & 255] = LBb[(size_t)task * 1024 + idx];
  for (int idx = tid; idx < 64 * 72 / 2; idx += 256) ((unsigned*)A_s)[idx] = 0;
  __syncthreads();
  for (int p = w; p < 10; p += 4) {
    const int I = (p >= 6) ? 3 : (p >= 3) ? 2 : (p >= 1) ? 1 : 0;
    const int J = p - (I * (I + 1)) / 2;
    f32x4 acc = {0.f, 0.f, 0.f, 0.f};
#pragma unroll
    for (int ks = 0; ks < 8; ++ks) {
      const int k0 = ks * 32 + fk;
      bf16x8 af = *(const bf16x8*)(qab + tbase + (size_t)(I * 16 + fr) * Kk + k0);
      if (I != J) {
#pragma unroll
        for (int e = 0; e < 8; ++e) {
          float d = exp2f(LB_s[I][k0 + e] - LB_s[J][k0 + e]);
          af[e] = (__bf16)((float)af[e] * d);
        }
      }
      bf16x8 bf = *(const bf16x8*)(kab + tbase + (size_t)(J * 16 + fr) * Kk + k0);
      acc = __builtin_amdgcn_mfma_f32_16x16x32_bf16(af, bf, acc, 0, 0, 0);
    }
#pragma unroll
    for (int r = 0; r < 4; ++r) {
      const int ml = fq * 4 + r, nl = fr;
      bool keep = (I != J) || (nl <= ml);
      A_s[I * 16 + ml][J * 16 + nl] = keep ? f2b(acc[r]) : (unsigned short)0;
    }
  }
  __syncthreads();
  f32x4 acc2[4][4] = {};
  const unsigned short* q2t = q2b + tbase;
  const unsigned short* s0t = S0Tb + (size_t)task * (Kk * Vv);
  const unsigned short* vtp = vTb + (size_t)b * (Vv * Tt) + (size_t)c * CC;
  const int vbase = w * 64;
#pragma unroll
  for (int ks = 0; ks < 8; ++ks) {
    const int k0 = ks * 32 + fk;
    bf16x8 af[4], bf[4];
#pragma unroll
    for (int i = 0; i < 4; ++i) af[i] = *(const bf16x8*)(q2t + (size_t)(i * 16 + fr) * Kk + k0);
#pragma unroll
    for (int j = 0; j < 4; ++j) bf[j] = *(const bf16x8*)(s0t + (size_t)(vbase + j * 16 + fr) * Kk + k0);
#pragma unroll
    for (int i = 0; i < 4; ++i)
#pragma unroll
      for (int j = 0; j < 4; ++j)
        acc2[i][j] = __builtin_amdgcn_mfma_f32_16x16x32_bf16(af[i], bf[j], acc2[i][j], 0, 0, 0);
  }
#pragma unroll
  for (int ks = 0; ks < 2; ++ks) {
    const int s0 = ks * 32 + fk;
    bf16x8 af[4], bf[4];
#pragma unroll
    for (int i = 0; i < 4; ++i) af[i] = *(const bf16x8*)&A_s[i * 16 + fr][s0];
#pragma unroll
    for (int j = 0; j < 4; ++j) bf[j] = *(const bf16x8*)(vtp + (size_t)(vbase + j * 16 + fr) * Tt + s0);
#pragma unroll
    for (int i = 0; i < 4; ++i)
#pragma unroll
      for (int j = 0; j < 4; ++j)
        acc2[i][j] = __builtin_amdgcn_mfma_f32_16x16x32_bf16(af[i], bf[j], acc2[i][j], 0, 0, 0);
  }
#pragma unroll
  for (int i = 0; i < 4; ++i)
#pragma unroll
    for (int j = 0; j < 4; ++j)
#pragma unroll
      for (int r = 0; r < 4; ++r)
        attb[((size_t)b * Tt + c * CC + i * 16 + fq * 4 + r) * Vv + vbase + j * 16 + fr]
            = f2b(acc2[i][j][r]);
}

extern "C" void kernel_launch(void* const* d_in, const int* in_sizes, int n_in,
                              void* d_out, int out_size, void* d_ws, size_t ws_size,
                              hipStream_t stream) {
  const float* hs = (const float*)d_in[0];
  const float* Wq = (const float*)d_in[1];
  const float* bq = (const float*)d_in[2];
  const float* Wk = (const float*)d_in[3];
  const float* bk = (const float*)d_in[4];
  const float* Wv = (const float*)d_in[5];
  const float* bv = (const float*)d_in[6];
  const float* Wg = (const float*)d_in[7];
  const float* bg = (const float*)d_in[8];
  const float* Wo = (const float*)d_in[9];
  const float* bo = (const float*)d_in[10];

  float* out = (float*)d_out;
  float* state_out = out + (size_t)Bb * Tt * Oo;

  char* p = (char*)d_ws;
  auto alloc = [&](size_t bytes) {
    char* r = p;
    p += (bytes + 255) & ~(size_t)255;
    return r;
  };
  unsigned short* hsb   = (unsigned short*)alloc((size_t)Bb * Tt * Hh * 2);   // 32MB
  unsigned short* WallT = (unsigned short*)alloc((size_t)1024 * Hh * 2);      // 2MB: [q|k|g|v] rows
  unsigned short* WoT   = (unsigned short*)alloc((size_t)Oo * Vv * 2);
  unsigned short* qb    = (unsigned short*)alloc((size_t)Bb * Tt * Kk * 2);   // 8MB each
  unsigned short* kb    = (unsigned short*)alloc((size_t)Bb * Tt * Kk * 2);
  unsigned short* lgb   = (unsigned short*)alloc((size_t)Bb * Tt * Kk * 2);   // f16
  unsigned short* vTb   = (unsigned short*)alloc((size_t)Bb * Vv * Tt * 2);
  unsigned short* attb  = (unsigned short*)alloc((size_t)Bb * Tt * Vv * 2);
  unsigned short* q2b   = (unsigned short*)alloc((size_t)Bb * Tt * Kk * 2);
  unsigned short* qab   = (unsigned short*)alloc((size_t)Bb * Tt * Kk * 2);
  unsigned short* kab   = (unsigned short*)alloc((size_t)Bb * Tt * Kk * 2);
  unsigned short* khTb  = (unsigned short*)alloc((size_t)Bb * NC * Kk * CC * 2);
  float*          LBb   = (float*)alloc((size_t)Bb * NC * 4 * Kk * 4);
  float*          Dendb = (float*)alloc((size_t)Bb * NC * Kk * 4);
  unsigned short* Sb    = (unsigned short*)alloc((size_t)Bb * NC * Kk * Vv * 2);  // 32MB
  unsigned short* S0Tb  = (unsigned short*)alloc((size_t)Bb * NC * Kk * Vv * 2);  // 32MB

  // 1) casts + weight transposes (concat projection weights into WallT rows)
  int n4 = Bb * Tt * Hh / 4;
  cast_bf16_kernel<<<(n4 + 255) / 256, 256, 0, stream>>>(hs, hsb, n4);
  transpose_cast_kernel<<<dim3(Hh / 32, Kk / 32), 256, 0, stream>>>(Wq, WallT + 0 * Kk * Hh, Hh, Kk);
  transpose_cast_kernel<<<dim3(Hh / 32, Kk / 32), 256, 0, stream>>>(Wk, WallT + 1 * Kk * Hh, Hh, Kk);
  transpose_cast_kernel<<<dim3(Hh / 32, Kk / 32), 256, 0, stream>>>(Wg, WallT + 2 * Kk * Hh, Hh, Kk);
  transpose_cast_kernel<<<dim3(Hh / 32, Kk / 32), 256, 0, stream>>>(Wv, WallT + 3 * Kk * Hh, Hh, Kk);
  transpose_cast_kernel<<<dim3(Vv / 32, Oo / 32), 256, 0, stream>>>(Wo, WoT, Vv, Oo);

  // 2) fused projections: one GEMM, N=1024, epilogue splits q/k/g/v (v transposed)
  gemm_fused_kernel<0><<<dim3(1024 / BN, (Bb * Tt) / BM), 256, 0, stream>>>(
      hsb, WallT, bq, bk, bg, bv, nullptr, qb, kb, lgb, vTb, Bb * Tt, 1024, Hh);

  // 3) prep (L cumsums, scaled tensors)
  prep_kernel<<<dim3(NC, Bb), 256, 0, stream>>>(qb, kb, lgb, q2b, qab, kab, khTb, LBb, Dendb);

  // 4) per-chunk state contribution S = khT . vT^T
  sgemm_kernel<<<dim3(NC, Bb), 256, 0, stream>>>(khTb, vTb, Sb);

  // 5) sequential chunk recombine -> S0T (pre-chunk states) + final state
  passR_kernel<<<dim3(Vv / 64, Kk / 64, Bb), 256, 0, stream>>>(Sb, Dendb, S0Tb, state_out);

  // 6) outputs: att = q2.S0 + tril(A).v
  passO_kernel<<<dim3(NC, Bb), 256, 0, stream>>>(qab, kab, q2b, LBb, S0Tb, vTb, attb);

  // 7) output projection (f32 out to d_out)
  gemm_fused_kernel<1><<<dim3(Oo / BN, (Bb * Tt) / BM), 256, 0, stream>>>(
      attb, WoT, bo, nullptr, nullptr, nullptr, out, nullptr, nullptr, nullptr, nullptr,
      Bb * Tt, Oo, Vv);
}

// Round 4
// 299.013 us; speedup vs baseline: 6.9126x; 1.0321x over previous
//
#include <hip/hip_runtime.h>

// Problem dims (fixed by setup_inputs)
#define Bb 8
#define Tt 2048
#define Hh 1024
#define Kk 256
#define Vv 256
#define Oo 1024
#define CC 64   // chunk length
#define NC 32   // chunks per batch (Tt/CC)

typedef __attribute__((ext_vector_type(8))) __bf16 bf16x8;
typedef __attribute__((ext_vector_type(4))) float f32x4;

__device__ __forceinline__ unsigned short f2b(float f) {
  unsigned u = __float_as_uint(f);
  u = (u + 0x7FFFu + ((u >> 16) & 1u)) >> 16;
  return (unsigned short)u;
}
__device__ __forceinline__ float b2f(unsigned short u) {
  return __uint_as_float(((unsigned)u) << 16);
}
__device__ __forceinline__ void gload_lds16(const unsigned short* g, unsigned short* l) {
  __builtin_amdgcn_global_load_lds(
      (const __attribute__((address_space(1))) void*)g,
      (__attribute__((address_space(3))) void*)l, 16, 0, 0);
}

// ---------------- cast f32 -> bf16 (vectorized) ----------------
__global__ __launch_bounds__(256) void cast_bf16_kernel(const float* __restrict__ in,
                                                        unsigned short* __restrict__ out,
                                                        int n4) {
  int i = blockIdx.x * 256 + threadIdx.x;
  if (i >= n4) return;
  float4 v = ((const float4*)in)[i];
  ushort4 o;
  o.x = f2b(v.x); o.y = f2b(v.y); o.z = f2b(v.z); o.w = f2b(v.w);
  ((ushort4*)out)[i] = o;
}

// ---------------- transpose + cast: W (H x N) f32 -> WT (N x H) bf16 ----------------
__global__ __launch_bounds__(256) void transpose_cast_kernel(const float* __restrict__ W,
                                                             unsigned short* __restrict__ WT,
                                                             int H, int N) {
  __shared__ float tile[32][33];
  int h0 = blockIdx.x * 32, n0 = blockIdx.y * 32;
  int tx = threadIdx.x & 31, ty = threadIdx.x >> 5;
  for (int r = ty; r < 32; r += 8)
    tile[r][tx] = W[(size_t)(h0 + r) * N + n0 + tx];
  __syncthreads();
  for (int r = ty; r < 32; r += 8)
    WT[(size_t)(n0 + r) * H + h0 + tx] = f2b(tile[tx][r]);
}

// ---------------- batched bf16 transpose: in (R x C) -> out (C x R), z = matrix idx ----
__global__ __launch_bounds__(256) void transpose_b16_kernel(
    const unsigned short* __restrict__ in, unsigned short* __restrict__ out,
    int R, int C) {
  __shared__ unsigned short tile[32][33];
  const int r0 = blockIdx.x * 32, c0 = blockIdx.y * 32;
  const size_t base = (size_t)blockIdx.z * R * C;
  const int tx = threadIdx.x & 31, ty = threadIdx.x >> 5;
  for (int rr = ty; rr < 32; rr += 8)
    tile[rr][tx] = in[base + (size_t)(r0 + rr) * C + c0 + tx];
  __syncthreads();
  for (int rr = ty; rr < 32; rr += 8)
    out[base + (size_t)(c0 + rr) * R + r0 + tx] = tile[tx][rr];
}

// ---------------- pipelined MFMA GEMM (T3 minimum 2-phase, double-buffered LDS) -------
// C = A (MxK, bf16 row-major) * Bt^T (Bt NxK bf16 row-major)
// MODE 0: fused projection epilogue: n>>8 selects {q, sigmoid->k, log2sig->g(f16), v}
// MODE 1: f32 out with bias b0p
#define BM 128
#define BN 128
#define BK 32

template <int MODE>
__global__ __launch_bounds__(256) void gemm_fused_kernel(
    const unsigned short* __restrict__ A, const unsigned short* __restrict__ Bt,
    const float* __restrict__ b0p, const float* __restrict__ b1p,
    const float* __restrict__ b2p, const float* __restrict__ b3p,
    float* __restrict__ Cf,
    unsigned short* __restrict__ O0, unsigned short* __restrict__ O1,
    unsigned short* __restrict__ O2, unsigned short* __restrict__ O3,
    int M, int N, int K) {
  __shared__ __align__(16) unsigned short As[2][BM * BK];
  __shared__ __align__(16) unsigned short Bs[2][BN * BK];
  const int tid = threadIdx.x;
  const int lane = tid & 63, wid = tid >> 6;
  const int wm = wid >> 1, wn = wid & 1;
  // XCD-aware bijective swizzle (nwg divisible by 8)
  const int nxt = gridDim.x;
  const int lin = blockIdx.x + blockIdx.y * nxt;
  const int cpx = (nxt * gridDim.y) >> 3;
  const int swz = (lin & 7) * cpx + (lin >> 3);
  const int m0 = (swz / nxt) * BM, n0 = (swz % nxt) * BN;
  const int fr = lane & 15, fq = lane >> 4, fk = fq * 8;
  // staging map: wave wid covers rows [32*wid, 32*wid+32) of each tile
  const int srow = 32 * wid + (lane >> 2);
  const int scol = (lane & 3) * 8;
  const unsigned short* gaBase = A + (size_t)(m0 + srow) * K + scol;
  const unsigned short* gbBase = Bt + (size_t)(n0 + srow) * K + scol;
  const int ldsA0 = (32 * wid) * BK, ldsA1 = (32 * wid + 16) * BK;

  f32x4 acc[4][4] = {};
  const int nt = K / BK;
  // prologue: stage tile 0 into buf 0
  gload_lds16(gaBase, &As[0][ldsA0]);
  gload_lds16(gaBase + 16 * (size_t)K, &As[0][ldsA1]);
  gload_lds16(gbBase, &Bs[0][ldsA0]);
  gload_lds16(gbBase + 16 * (size_t)K, &Bs[0][ldsA1]);
  __syncthreads();  // vmcnt(0) drain + barrier
  int cur = 0;
  for (int t = 0; t < nt; ++t) {
    if (t + 1 < nt) {  // stage next tile into other buffer (overlaps with compute)
      const int k0 = (t + 1) * BK;
      gload_lds16(gaBase + k0, &As[cur ^ 1][ldsA0]);
      gload_lds16(gaBase + k0 + 16 * (size_t)K, &As[cur ^ 1][ldsA1]);
      gload_lds16(gbBase + k0, &Bs[cur ^ 1][ldsA0]);
      gload_lds16(gbBase + k0 + 16 * (size_t)K, &Bs[cur ^ 1][ldsA1]);
    }
    bf16x8 af[4], bfv[4];
#pragma unroll
    for (int i = 0; i < 4; ++i)
      af[i] = *(const bf16x8*)&As[cur][(wm * 64 + i * 16 + fr) * BK + fk];
#pragma unroll
    for (int i = 0; i < 4; ++i)
      bfv[i] = *(const bf16x8*)&Bs[cur][(wn * 64 + i * 16 + fr) * BK + fk];
#pragma unroll
    for (int i = 0; i < 4; ++i)
#pragma unroll
      for (int j = 0; j < 4; ++j)
        acc[i][j] = __builtin_amdgcn_mfma_f32_16x16x32_bf16(af[i], bfv[j], acc[i][j], 0, 0, 0);
    __syncthreads();  // drains vmcnt(0): next buffer staged & all frag reads done
    cur ^= 1;
  }
#pragma unroll
  for (int j = 0; j < 4; ++j) {
    const int n = n0 + wn * 64 + j * 16 + fr;
    if (MODE == 1) {
      const float bv = b0p[n];
#pragma unroll
      for (int i = 0; i < 4; ++i) {
        const int mb = m0 + wm * 64 + i * 16 + fq * 4;
#pragma unroll
        for (int r = 0; r < 4; ++r)
          Cf[(size_t)(mb + r) * N + n] = acc[i][j][r] + bv;
      }
    } else {
      const int sel = n >> 8, nl = n & 255;
      const float bv = sel == 0 ? b0p[nl] : sel == 1 ? b1p[nl] : sel == 2 ? b2p[nl] : b3p[nl];
#pragma unroll
      for (int i = 0; i < 4; ++i) {
        const int mb = m0 + wm * 64 + i * 16 + fq * 4;
#pragma unroll
        for (int r = 0; r < 4; ++r) {
          const int m = mb + r;
          const float x = acc[i][j][r] + bv;
          if (sel == 0) {
            O0[(size_t)m * Kk + nl] = f2b(x);
          } else if (sel == 1) {
            O1[(size_t)m * Kk + nl] = f2b(1.f / (1.f + expf(-x)));
          } else if (sel == 2) {
            float e = exp2f(-x * 1.44269504f);
            float lg = -log2f(1.f + e);
            _Float16 hv = (_Float16)lg;
            unsigned short u;
            __builtin_memcpy(&u, &hv, 2);
            O2[(size_t)m * Kk + nl] = u;
          } else {  // v plain (coalesced); transposed later by transpose_b16
            O3[(size_t)m * Vv + nl] = f2b(x);
          }
        }
      }
    }
  }
}

// ---------------- fused prep+sgemm: per (b,c) task ----------------
// phase 1 (thread=k): L cumsums, scaled q/k variants; khT staged in LDS (padded)
// phase 2 (4 waves): S[task][k][v] = sum_s khT[k][s] * vT[v][s]
__global__ __launch_bounds__(256) void prep_sgemm_kernel(
    const unsigned short* __restrict__ qb, const unsigned short* __restrict__ kb,
    const unsigned short* __restrict__ lgb, const unsigned short* __restrict__ vTb,
    unsigned short* __restrict__ q2b, unsigned short* __restrict__ qab,
    unsigned short* __restrict__ kab,
    float* __restrict__ LBb, float* __restrict__ Dendb,
    unsigned short* __restrict__ Sb) {
  __shared__ __align__(16) unsigned short khs[256][72];  // pad 72: 144B rows, 16B-aligned
  const int c = blockIdx.x, b = blockIdx.y;
  const int k = threadIdx.x;
  const int task = b * NC + c;
  const size_t rowbase = ((size_t)b * Tt + (size_t)c * CC) * Kk + k;
  // ---- phase 1: prep ----
  float Ls = 0.f;
  float LBr[4];
#pragma unroll
  for (int gq = 0; gq < 4; ++gq) {
    LBr[gq] = Ls;
#pragma unroll
    for (int tt = 0; tt < 16; ++tt) {
      int t = gq * 16 + tt;
      _Float16 hv;
      __builtin_memcpy(&hv, &lgb[rowbase + (size_t)t * Kk], 2);
      Ls += (float)hv;
    }
  }
  const float Lend = Ls;
#pragma unroll
  for (int gq = 0; gq < 4; ++gq) LBb[(size_t)task * 1024 + gq * 256 + k] = LBr[gq];
  Dendb[task * 256 + k] = exp2f(Lend);
  float L = 0.f;
#pragma unroll
  for (int gq = 0; gq < 4; ++gq) {
    const float LBc = LBr[gq];
    unsigned kw[8];
#pragma unroll
    for (int tt = 0; tt < 16; ++tt) {
      int t = gq * 16 + tt;
      size_t off = rowbase + (size_t)t * Kk;
      _Float16 hv;
      __builtin_memcpy(&hv, &lgb[off], 2);
      L += (float)hv;
      float qv = b2f(qb[off]);
      float kv = b2f(kb[off]);
      q2b[off] = f2b(qv * exp2f(L));
      qab[off] = f2b(qv * exp2f(L - LBc));
      kab[off] = f2b(kv * exp2f(LBc - L));
      unsigned short kh = f2b(kv * exp2f(Lend - L));
      if (tt & 1) kw[tt >> 1] |= ((unsigned)kh) << 16;
      else        kw[tt >> 1] = kh;
    }
    uint4 u0; u0.x = kw[0]; u0.y = kw[1]; u0.z = kw[2]; u0.w = kw[3];
    uint4 u1; u1.x = kw[4]; u1.y = kw[5]; u1.z = kw[6]; u1.w = kw[7];
    *(uint4*)&khs[k][gq * 16] = u0;
    *(uint4*)&khs[k][gq * 16 + 8] = u1;
  }
  __syncthreads();
  // ---- phase 2: sgemm ----
  const int tid = threadIdx.x, lane = tid & 63, w = tid >> 6;
  const int fr = lane & 15, fq = lane >> 4, fk = fq * 8;
  const unsigned short* vt = vTb + (size_t)b * (Vv * Tt) + (size_t)c * CC;
  for (int vb4 = 0; vb4 < 4; ++vb4) {
    f32x4 acc[4][4] = {};
#pragma unroll
    for (int ks = 0; ks < 2; ++ks) {
      bf16x8 af[4], bf[4];
#pragma unroll
      for (int i = 0; i < 4; ++i)
        af[i] = *(const bf16x8*)&khs[w * 64 + i * 16 + fr][ks * 32 + fk];
#pragma unroll
      for (int j = 0; j < 4; ++j)
        bf[j] = *(const bf16x8*)(vt + (size_t)(vb4 * 64 + j * 16 + fr) * Tt + ks * 32 + fk);
#pragma unroll
      for (int i = 0; i < 4; ++i)
#pragma unroll
        for (int j = 0; j < 4; ++j)
          acc[i][j] = __builtin_amdgcn_mfma_f32_16x16x32_bf16(af[i], bf[j], acc[i][j], 0, 0, 0);
    }
#pragma unroll
    for (int i = 0; i < 4; ++i)
#pragma unroll
      for (int j = 0; j < 4; ++j)
#pragma unroll
        for (int r = 0; r < 4; ++r)
          Sb[(size_t)task * (Kk * Vv) + (size_t)(w * 64 + i * 16 + fq * 4 + r) * Vv +
             vb4 * 64 + j * 16 + fr] = f2b(acc[i][j][r]);
  }
}

// ---------------- passR: sequential chunk recombine (parallel over B,K,V) ----------------
__global__ __launch_bounds__(256) void passR_kernel(
    const unsigned short* __restrict__ Sb, const float* __restrict__ Dendb,
    unsigned short* __restrict__ S0Tb, float* __restrict__ state_out) {
  const int vt = blockIdx.x, kt = blockIdx.y, b = blockIdx.z;
  const int tid = threadIdx.x;
  const int kq = tid >> 2;
  const int vq = tid & 3;
  const int vr = tid >> 2;
  const int kqq = tid & 3;
  __shared__ __align__(16) unsigned short Ts[64][72];
  float st[16];
#pragma unroll
  for (int j = 0; j < 16; ++j) st[j] = 0.f;
  for (int c = 0; c < NC; ++c) {
    const int task = b * NC + c;
#pragma unroll
    for (int j = 0; j < 16; ++j) Ts[vq * 16 + j][kq] = f2b(st[j]);
    __syncthreads();
    {
      unsigned short* dst = S0Tb + (size_t)task * (Kk * Vv) +
                            (size_t)(vt * 64 + vr) * Kk + kt * 64 + kqq * 16;
      *(uint4*)dst = *(const uint4*)&Ts[vr][kqq * 16];
      *(uint4*)(dst + 8) = *(const uint4*)&Ts[vr][kqq * 16 + 8];
    }
    __syncthreads();
    const float d = Dendb[task * 256 + kt * 64 + kq];
    const unsigned short* sp = Sb + (size_t)task * (Kk * Vv) +
                               (size_t)(kt * 64 + kq) * Vv + vt * 64 + vq * 16;
#pragma unroll
    for (int h = 0; h < 2; ++h) {
      uint4 raw = *(const uint4*)(sp + h * 8);
      unsigned ws_[4] = {raw.x, raw.y, raw.z, raw.w};
#pragma unroll
      for (int e = 0; e < 4; ++e) {
        float lo = __uint_as_float(ws_[e] << 16);
        float hi = __uint_as_float(ws_[e] & 0xFFFF0000u);
        st[h * 8 + e * 2]     = d * st[h * 8 + e * 2] + lo;
        st[h * 8 + e * 2 + 1] = d * st[h * 8 + e * 2 + 1] + hi;
      }
    }
  }
  float* so = state_out + (size_t)(b * Kk + kt * 64 + kq) * Vv + vt * 64 + vq * 16;
#pragma unroll
  for (int j = 0; j < 16; ++j) so[j] = st[j];
}

// ---------------- passO: per (b,c): att = q2*S0 + tril(A)*v ----------------
__global__ __launch_bounds__(256) void passO_kernel(
    const unsigned short* __restrict__ qab, const unsigned short* __restrict__ kab,
    const unsigned short* __restrict__ q2b, const float* __restrict__ LBb,
    const unsigned short* __restrict__ S0Tb, const unsigned short* __restrict__ vTb,
    unsigned short* __restrict__ attb) {
  const int c = blockIdx.x, b = blockIdx.y;
  const int task = b * NC + c;
  const int tid = threadIdx.x, lane = tid & 63, w = tid >> 6;
  const int fr = lane & 15, fq = lane >> 4, fk = fq * 8;
  __shared__ float LB_s[4][256];
  __shared__ __align__(16) unsigned short A_s[64][72];
  const size_t tbase = (size_t)task * (CC * Kk);
  for (int idx = tid; idx < 1024; idx += 256) LB_s[idx >> 8][idx & 255] = LBb[(size_t)task * 1024 + idx];
  for (int idx = tid; idx < 64 * 72 / 2; idx += 256) ((unsigned*)A_s)[idx] = 0;
  __syncthreads();
  for (int p = w; p < 10; p += 4) {
    const int I = (p >= 6) ? 3 : (p >= 3) ? 2 : (p >= 1) ? 1 : 0;
    const int J = p - (I * (I + 1)) / 2;
    f32x4 acc = {0.f, 0.f, 0.f, 0.f};
#pragma unroll
    for (int ks = 0; ks < 8; ++ks) {
      const int k0 = ks * 32 + fk;
      bf16x8 af = *(const bf16x8*)(qab + tbase + (size_t)(I * 16 + fr) * Kk + k0);
      if (I != J) {
#pragma unroll
        for (int e = 0; e < 8; ++e) {
          float d = exp2f(LB_s[I][k0 + e] - LB_s[J][k0 + e]);
          af[e] = (__bf16)((float)af[e] * d);
        }
      }
      bf16x8 bf = *(const bf16x8*)(kab + tbase + (size_t)(J * 16 + fr) * Kk + k0);
      acc = __builtin_amdgcn_mfma_f32_16x16x32_bf16(af, bf, acc, 0, 0, 0);
    }
#pragma unroll
    for (int r = 0; r < 4; ++r) {
      const int ml = fq * 4 + r, nl = fr;
      bool keep = (I != J) || (nl <= ml);
      A_s[I * 16 + ml][J * 16 + nl] = keep ? f2b(acc[r]) : (unsigned short)0;
    }
  }
  __syncthreads();
  f32x4 acc2[4][4] = {};
  const unsigned short* q2t = q2b + tbase;
  const unsigned short* s0t = S0Tb + (size_t)task * (Kk * Vv);
  const unsigned short* vtp = vTb + (size_t)b * (Vv * Tt) + (size_t)c * CC;
  const int vbase = w * 64;
#pragma unroll
  for (int ks = 0; ks < 8; ++ks) {
    const int k0 = ks * 32 + fk;
    bf16x8 af[4], bf[4];
#pragma unroll
    for (int i = 0; i < 4; ++i) af[i] = *(const bf16x8*)(q2t + (size_t)(i * 16 + fr) * Kk + k0);
#pragma unroll
    for (int j = 0; j < 4; ++j) bf[j] = *(const bf16x8*)(s0t + (size_t)(vbase + j * 16 + fr) * Kk + k0);
#pragma unroll
    for (int i = 0; i < 4; ++i)
#pragma unroll
      for (int j = 0; j < 4; ++j)
        acc2[i][j] = __builtin_amdgcn_mfma_f32_16x16x32_bf16(af[i], bf[j], acc2[i][j], 0, 0, 0);
  }
#pragma unroll
  for (int ks = 0; ks < 2; ++ks) {
    const int s0 = ks * 32 + fk;
    bf16x8 af[4], bf[4];
#pragma unroll
    for (int i = 0; i < 4; ++i) af[i] = *(const bf16x8*)&A_s[i * 16 + fr][s0];
#pragma unroll
    for (int j = 0; j < 4; ++j) bf[j] = *(const bf16x8*)(vtp + (size_t)(vbase + j * 16 + fr) * Tt + s0);
#pragma unroll
    for (int i = 0; i < 4; ++i)
#pragma unroll
      for (int j = 0; j < 4; ++j)
        acc2[i][j] = __builtin_amdgcn_mfma_f32_16x16x32_bf16(af[i], bf[j], acc2[i][j], 0, 0, 0);
  }
#pragma unroll
  for (int i = 0; i < 4; ++i)
#pragma unroll
    for (int j = 0; j < 4; ++j)
#pragma unroll
      for (int r = 0; r < 4; ++r)
        attb[((size_t)b * Tt + c * CC + i * 16 + fq * 4 + r) * Vv + vbase + j * 16 + fr]
            = f2b(acc2[i][j][r]);
}

extern "C" void kernel_launch(void* const* d_in, const int* in_sizes, int n_in,
                              void* d_out, int out_size, void* d_ws, size_t ws_size,
                              hipStream_t stream) {
  const float* hs = (const float*)d_in[0];
  const float* Wq = (const float*)d_in[1];
  const float* bq = (const float*)d_in[2];
  const float* Wk = (const float*)d_in[3];
  const float* bk = (const float*)d_in[4];
  const float* Wv = (const float*)d_in[5];
  const float* bv = (const float*)d_in[6];
  const float* Wg = (const float*)d_in[7];
  const float* bg = (const float*)d_in[8];
  const float* Wo = (const float*)d_in[9];
  const float* bo = (const float*)d_in[10];

  float* out = (float*)d_out;
  float* state_out = out + (size_t)Bb * Tt * Oo;

  char* p = (char*)d_ws;
  auto alloc = [&](size_t bytes) {
    char* r = p;
    p += (bytes + 255) & ~(size_t)255;
    return r;
  };
  unsigned short* hsb   = (unsigned short*)alloc((size_t)Bb * Tt * Hh * 2);   // 32MB
  unsigned short* WallT = (unsigned short*)alloc((size_t)1024 * Hh * 2);      // 2MB
  unsigned short* WoT   = (unsigned short*)alloc((size_t)Oo * Vv * 2);
  unsigned short* qb    = (unsigned short*)alloc((size_t)Bb * Tt * Kk * 2);   // 8MB each
  unsigned short* kb    = (unsigned short*)alloc((size_t)Bb * Tt * Kk * 2);
  unsigned short* lgb   = (unsigned short*)alloc((size_t)Bb * Tt * Kk * 2);   // f16
  unsigned short* vb    = (unsigned short*)alloc((size_t)Bb * Tt * Vv * 2);
  unsigned short* vTb   = (unsigned short*)alloc((size_t)Bb * Vv * Tt * 2);
  unsigned short* attb  = (unsigned short*)alloc((size_t)Bb * Tt * Vv * 2);
  unsigned short* q2b   = (unsigned short*)alloc((size_t)Bb * Tt * Kk * 2);
  unsigned short* qab   = (unsigned short*)alloc((size_t)Bb * Tt * Kk * 2);
  unsigned short* kab   = (unsigned short*)alloc((size_t)Bb * Tt * Kk * 2);
  float*          LBb   = (float*)alloc((size_t)Bb * NC * 4 * Kk * 4);
  float*          Dendb = (float*)alloc((size_t)Bb * NC * Kk * 4);
  unsigned short* Sb    = (unsigned short*)alloc((size_t)Bb * NC * Kk * Vv * 2);  // 32MB
  unsigned short* S0Tb  = (unsigned short*)alloc((size_t)Bb * NC * Kk * Vv * 2);  // 32MB

  // 1) casts + weight transposes (concat projection weights into WallT rows)
  int n4 = Bb * Tt * Hh / 4;
  cast_bf16_kernel<<<(n4 + 255) / 256, 256, 0, stream>>>(hs, hsb, n4);
  transpose_cast_kernel<<<dim3(Hh / 32, Kk / 32), 256, 0, stream>>>(Wq, WallT + 0 * Kk * Hh, Hh, Kk);
  transpose_cast_kernel<<<dim3(Hh / 32, Kk / 32), 256, 0, stream>>>(Wk, WallT + 1 * Kk * Hh, Hh, Kk);
  transpose_cast_kernel<<<dim3(Hh / 32, Kk / 32), 256, 0, stream>>>(Wg, WallT + 2 * Kk * Hh, Hh, Kk);
  transpose_cast_kernel<<<dim3(Hh / 32, Kk / 32), 256, 0, stream>>>(Wv, WallT + 3 * Kk * Hh, Hh, Kk);
  transpose_cast_kernel<<<dim3(Vv / 32, Oo / 32), 256, 0, stream>>>(Wo, WoT, Vv, Oo);

  // 2) fused projections: one GEMM, N=1024, epilogue splits q/k/g/v
  gemm_fused_kernel<0><<<dim3(1024 / BN, (Bb * Tt) / BM), 256, 0, stream>>>(
      hsb, WallT, bq, bk, bg, bv, nullptr, qb, kb, lgb, vb, Bb * Tt, 1024, Hh);

  // 3) vT: per-batch transpose (T x V -> V x T)
  transpose_b16_kernel<<<dim3(Tt / 32, Vv / 32, Bb), 256, 0, stream>>>(vb, vTb, Tt, Vv);

  // 4) fused prep + per-chunk state GEMM
  prep_sgemm_kernel<<<dim3(NC, Bb), 256, 0, stream>>>(qb, kb, lgb, vTb, q2b, qab, kab,
                                                      LBb, Dendb, Sb);

  // 5) sequential chunk recombine -> S0T (pre-chunk states) + final state
  passR_kernel<<<dim3(Vv / 64, Kk / 64, Bb), 256, 0, stream>>>(Sb, Dendb, S0Tb, state_out);

  // 6) outputs: att = q2.S0 + tril(A).v
  passO_kernel<<<dim3(NC, Bb), 256, 0, stream>>>(qab, kab, q2b, LBb, S0Tb, vTb, attb);

  // 7) output projection (f32 out to d_out)
  gemm_fused_kernel<1><<<dim3(Oo / BN, (Bb * Tt) / BM), 256, 0, stream>>>(
      attb, WoT, bo, nullptr, nullptr, nullptr, out, nullptr, nullptr, nullptr, nullptr,
      Bb * Tt, Oo, Vv);
}